// Round 10
// baseline (160.562 us; speedup 1.0000x reference)
//
#include <hip/hip_runtime.h>
#include <math.h>

#define BB 2
#define CC 512
#define NN 2304
#define NH 8
#define DD 512
#define D3 1536
#define WIDTH 48
#define C1 0.18033688f  // 0.125 * log2(e)

#define KSPLIT 2
#define KTILES 18        // 36 / KSPLIT
#define NTBL 213         // 71 deltas * 3 (qt mod 3)

typedef _Float16 h8 __attribute__((ext_vector_type(8)));
typedef _Float16 h4 __attribute__((ext_vector_type(4)));
typedef _Float16 h2 __attribute__((ext_vector_type(2)));
typedef float f4 __attribute__((ext_vector_type(4)));

__device__ __forceinline__ void gload16(const void* g, void* s) {
  __builtin_amdgcn_global_load_lds(
      (const __attribute__((address_space(1))) unsigned int*)g,
      (__attribute__((address_space(3))) unsigned int*)s, 16, 0, 0);
}

// ---------------------------------------------------------------------------
// Kernel 0 (merged prep): x transpose->f16, weight converts, Fresnel bias
// table (f16, dedup'd: entry depends only on (qt-kt, qt mod 3) since
// (qt,kt)->(qt+3,kt+3) shifts both tokens by 192 = 4 full rows).
// Table tbl = (qt-kt+35)*3 + qt%3, layout per tbl: [tid 128][j 32] in MFMA
// C-fragment order, pre-scaled by 0.1*log2e.
// ---------------------------------------------------------------------------
__global__ __launch_bounds__(256) void prep_k(
    const float* __restrict__ x, const float* __restrict__ wq,
    const float* __restrict__ wo, const float* __restrict__ wavp,
    _Float16* __restrict__ xt, _Float16* __restrict__ wqh,
    _Float16* __restrict__ woh, _Float16* __restrict__ btf)
{
  __shared__ float Ls[32][33];
  const int t = threadIdx.x;
  const int e = blockIdx.x;

  if (e < 2304) {
    // ---- transpose-convert x[b][c][n] fp32 -> xt[b][n][c] f16 ----
    const int n0 = (e % 72) * 32;
    const int c0 = ((e / 72) % 16) * 32;
    const int b  = e / 1152;
#pragma unroll
    for (int p = 0; p < 4; ++p) {
      const int cl = (t >> 5) + p * 8, nl = t & 31;
      Ls[cl][nl] = x[((size_t)b * CC + c0 + cl) * NN + n0 + nl];
    }
    __syncthreads();
#pragma unroll
    for (int p = 0; p < 2; ++p) {
      const int nl = (t >> 4) + p * 16, cl = (t & 15) * 2;
      h2 v = {(_Float16)Ls[cl][nl], (_Float16)Ls[cl + 1][nl]};
      *(h2*)(xt + ((size_t)b * NN + n0 + nl) * CC + c0 + cl) = v;
    }
  } else if (e < 3328) {
    // ---- convert w_qkv and w_out fp32 -> f16 ----
    const int idx = (e - 2304) * 256 + t;
    const int NQ = (D3 * CC) / 4;
    if (idx < NQ) {
      float4 v = *(const float4*)(wq + (size_t)idx * 4);
      h4 o = {(_Float16)v.x, (_Float16)v.y, (_Float16)v.z, (_Float16)v.w};
      *(h4*)(wqh + (size_t)idx * 4) = o;
    } else {
      const int j = idx - NQ;
      float4 v = *(const float4*)(wo + (size_t)j * 4);
      h4 o = {(_Float16)v.x, (_Float16)v.y, (_Float16)v.z, (_Float16)v.w};
      *(h4*)(woh + (size_t)j * 4) = o;
    }
  } else {
    // ---- Fresnel bias tables f16 (2 tables per 256-thread block) ----
    const int tbl = (e - 3328) * 2 + (t >> 7);
    if (tbl < NTBL) {
      const int tid = t & 127;
      const int dD = tbl / 3, qm = tbl % 3;
      const int qt0 = qm + 36;          // representative qtile, == qm (mod 3)
      const int kt0 = qt0 - (dD - 35);  // >= 1, keeps token indices positive
      const int w = tid >> 6, quad = (tid >> 4) & 3, l15 = tid & 15;
      const float pc = 6.283185307179586f / (fabsf(wavp[0]) * (float)WIDTH + 1e-6f);
      _Float16* o = btf + ((size_t)tbl * 128 + tid) * 32;
#pragma unroll
      for (int g = 0; g < 4; ++g) {
        h8 v;
#pragma unroll
        for (int el = 0; el < 8; ++el) {
          const int j = g * 8 + el;
          const int nt = j >> 4, mt = (j >> 2) & 3, r = j & 3;
          const int q = qt0 * 64 + w * 32 + nt * 16 + l15;
          const int k = kt0 * 64 + mt * 16 + quad * 4 + r;
          const float dy = (float)(q / WIDTH) - (float)(k / WIDTH);
          const float dx = (float)(q % WIDTH) - (float)(k % WIDTH);
          const float dist = sqrtf(dy * dy + dx * dx + 1e-8f);
          v[el] = (_Float16)(0.1f * __cosf(dist * pc) * 1.44269504f);
        }
        *(h8*)(o + g * 8) = v;
      }
    }
  }
}

// ---------------------------------------------------------------------------
// Kernel 1: qkv MFMA GEMM, 128(n) x 64(d) tiles, BK=64 via two 32-wide slabs
// per barrier pair (per-slab layout identical to proven BK=32 pattern).
// 8 k-phases x 16 MFMA (was 16 x 8): half the barriers, double the MFMA
// density per phase. Q written pre-scaled by C1 (exp2 domain).
// ---------------------------------------------------------------------------
__global__ __launch_bounds__(256) void qkv_gemm_k(
    const _Float16* __restrict__ xt, const _Float16* __restrict__ wqh,
    _Float16* __restrict__ qb, _Float16* __restrict__ kb,
    _Float16* __restrict__ vb)
{
  __shared__ _Float16 Xs[2][128][32];
  __shared__ _Float16 Ws[2][64][32];
  const int t = threadIdx.x;
  const int lane = t & 63, w = t >> 6;
  const int l15 = lane & 15, quad = lane >> 4;
  const int wm = w & 1;    // d half (32 wide)
  const int wn = w >> 1;   // n half (64 wide)
  const int n0 = blockIdx.x * 128;
  const int d0 = blockIdx.y * 64;
  const int b  = blockIdx.z;
  const bool isv = (d0 >= 2 * DD);
  const _Float16* xb = xt + (size_t)b * NN * CC;

  const int srow = lane >> 2, scol = (lane & 3) * 8;

  f4 acc[2][4];  // [mt: d][nt: n]
#pragma unroll
  for (int mt = 0; mt < 2; ++mt)
#pragma unroll
    for (int nt = 0; nt < 4; ++nt) acc[mt][nt] = (f4)(0.f);

  for (int c0 = 0; c0 < CC; c0 += 64) {
#pragma unroll
    for (int s = 0; s < 2; ++s) {
#pragma unroll
      for (int r = 0; r < 2; ++r) {
        const int ci = w + r * 4;
        gload16(xb + (size_t)(n0 + ci * 16 + srow) * CC + c0 + s * 32 + scol,
                &Xs[s][0][0] + ci * 512);
      }
      gload16(wqh + (size_t)(d0 + w * 16 + srow) * CC + c0 + s * 32 + scol,
              &Ws[s][0][0] + w * 512);
    }
    __syncthreads();

    h8 wfr[2][2], xfr[4][2];
#pragma unroll
    for (int s = 0; s < 2; ++s) {
#pragma unroll
      for (int mt = 0; mt < 2; ++mt)
        wfr[mt][s] = *(const h8*)&Ws[s][wm * 32 + mt * 16 + l15][quad * 8];
#pragma unroll
      for (int nt = 0; nt < 4; ++nt)
        xfr[nt][s] = *(const h8*)&Xs[s][wn * 64 + nt * 16 + l15][quad * 8];
    }

    if (!isv) {
#pragma unroll
      for (int s = 0; s < 2; ++s)
#pragma unroll
        for (int mt = 0; mt < 2; ++mt)
#pragma unroll
          for (int nt = 0; nt < 4; ++nt)
            acc[mt][nt] = __builtin_amdgcn_mfma_f32_16x16x32_f16(
                wfr[mt][s], xfr[nt][s], acc[mt][nt], 0, 0, 0);
    } else {
#pragma unroll
      for (int s = 0; s < 2; ++s)
#pragma unroll
        for (int mt = 0; mt < 2; ++mt)
#pragma unroll
          for (int nt = 0; nt < 4; ++nt)
            acc[mt][nt] = __builtin_amdgcn_mfma_f32_16x16x32_f16(
                xfr[nt][s], wfr[mt][s], acc[mt][nt], 0, 0, 0);
    }
    __syncthreads();
  }

  if (!isv) {
    const int which = d0 >> 9;
    _Float16* buf = which == 0 ? qb : kb;
    const float qs = (which == 0) ? C1 : 1.0f;  // fold softmax scale into Q
    const int h = (d0 & 511) >> 6;
#pragma unroll
    for (int mt = 0; mt < 2; ++mt) {
      const int dh = wm * 32 + mt * 16 + quad * 4;
#pragma unroll
      for (int nt = 0; nt < 4; ++nt) {
        const int token = n0 + wn * 64 + nt * 16 + l15;
        h4 o = {(_Float16)(acc[mt][nt][0] * qs), (_Float16)(acc[mt][nt][1] * qs),
                (_Float16)(acc[mt][nt][2] * qs), (_Float16)(acc[mt][nt][3] * qs)};
        *(h4*)(buf + (((size_t)b * NH + h) * NN + token) * 64 + dh) = o;
      }
    }
  } else {
    const int h = (d0 - 2 * DD) >> 6;
#pragma unroll
    for (int mt = 0; mt < 2; ++mt) {
      const int dh = wm * 32 + mt * 16 + l15;
#pragma unroll
      for (int nt = 0; nt < 4; ++nt) {
        const int token = n0 + wn * 64 + nt * 16 + quad * 4;
        h4 o = {(_Float16)acc[mt][nt][0], (_Float16)acc[mt][nt][1],
                (_Float16)acc[mt][nt][2], (_Float16)acc[mt][nt][3]};
        *(h4*)(vb + (((size_t)b * NH + h) * 64 + dh) * NN + token) = o;
      }
    }
  }
}

// ---------------------------------------------------------------------------
// Kernel 2: MFMA flash attention — EXACT R4/R9 champion (61.4 us measured).
// 128 Q-rows per block (4 waves), K-split x2, f16 bias seeds S accumulator,
// Ps rows wave-private. LDS 36.9 KB.
// ---------------------------------------------------------------------------
__global__ __launch_bounds__(256, 4) void attn_k(
    const _Float16* __restrict__ qb, const _Float16* __restrict__ kb,
    const _Float16* __restrict__ vb, const _Float16* __restrict__ btf,
    _Float16* __restrict__ op, float* __restrict__ lp)
{
  __shared__ _Float16 Ks[64][72];
  __shared__ _Float16 Vs[64][72];
  __shared__ _Float16 Ps[128][72];

  const int t    = threadIdx.x;
  const int lane = t & 63;
  const int w    = t >> 6;          // wave 0..3 -> local q rows w*32..w*32+31
  const int l15  = lane & 15;
  const int quad = lane >> 4;
  const int qpair = blockIdx.x >> 1;   // 128-row Q block index (0..17)
  const int kq    = blockIdx.x & 1;    // K-split half
  const int n0 = qpair * 128;
  const int qtile = qpair * 2 + (w >> 1);  // 64-row tile this wave sits in
  const int h  = blockIdx.y;
  const int b  = blockIdx.z;
  const size_t base = ((size_t)b * NH + h) * NN * 64;
  const _Float16* qp = qb + base;
  const _Float16* kp = kb + base;
  const _Float16* vp = vb + base;  // [dh][n]

  h8 qf[2][2];
#pragma unroll
  for (int nt = 0; nt < 2; ++nt)
#pragma unroll
    for (int ks = 0; ks < 2; ++ks)
      qf[nt][ks] = *(const h8*)(qp + (size_t)(n0 + w * 32 + nt * 16 + l15) * 64 +
                                ks * 32 + quad * 8);

  f4 oc[4][2];
#pragma unroll
  for (int mt = 0; mt < 4; ++mt)
#pragma unroll
    for (int nt = 0; nt < 2; ++nt) oc[mt][nt] = (f4)(0.f);
  float lac[2][2] = {};

  // bias table ptr: tbl = (qtile - ktile + 35)*3 + qtile%3; within-table tid
  // = (w&1)*64 + lane (the 128-tid layout's q-half select is our w&1).
  const _Float16* bp =
      btf + ((size_t)((qtile - kq * KTILES + 35) * 3 + qtile % 3) * 128 +
             (w & 1) * 64 + lane) * 32;

  for (int kt = 0; kt < KTILES; ++kt) {
    const int k0 = (kq * KTILES + kt) * 64;
    h8 kr[2], vr[2], bfr[4];
#pragma unroll
    for (int r = 0; r < 2; ++r) {
      const int c = t + r * 256;
      const int row = c >> 3, off = (c & 7) * 8;
      kr[r] = *(const h8*)(kp + (size_t)(k0 + row) * 64 + off);
      vr[r] = *(const h8*)(vp + (size_t)row * NN + k0 + off);
    }
#pragma unroll
    for (int r = 0; r < 4; ++r) bfr[r] = *(const h8*)(bp + r * 8);
    bp -= 3 * 128 * 32;  // next ktile: delta decreases by 1 -> tbl index -3
    __syncthreads();
#pragma unroll
    for (int r = 0; r < 2; ++r) {
      const int c = t + r * 256;
      const int row = c >> 3, off = (c & 7) * 8;
      *(h8*)&Ks[row][off] = kr[r];
      *(h8*)&Vs[row][off] = vr[r];
    }
    __syncthreads();

    // ---- S^T = K * Q'^T, accumulator seeded with bias fragment ----
    f4 st[4][2];
#pragma unroll
    for (int mt = 0; mt < 4; ++mt)
#pragma unroll
      for (int nt = 0; nt < 2; ++nt) {
        const int jb = nt * 16 + mt * 4;
        f4 s = {(float)bfr[jb >> 3][(jb & 7) + 0],
                (float)bfr[jb >> 3][(jb & 7) + 1],
                (float)bfr[jb >> 3][(jb & 7) + 2],
                (float)bfr[jb >> 3][(jb & 7) + 3]};
        st[mt][nt] = s;
      }
#pragma unroll
    for (int ks = 0; ks < 2; ++ks) {
#pragma unroll
      for (int mt = 0; mt < 4; ++mt) {
        h8 kf = *(const h8*)&Ks[mt * 16 + l15][ks * 32 + quad * 8];
#pragma unroll
        for (int nt = 0; nt < 2; ++nt)
          st[mt][nt] = __builtin_amdgcn_mfma_f32_16x16x32_f16(
              kf, qf[nt][ks], st[mt][nt], 0, 0, 0);
      }
    }

    // ---- p = exp2(s), no max tracking ----
#pragma unroll
    for (int nt = 0; nt < 2; ++nt) {
      const int q = w * 32 + nt * 16 + l15;
#pragma unroll
      for (int mt = 0; mt < 4; ++mt) {
        const float p0 = __builtin_exp2f(st[mt][nt][0]);
        const float p1 = __builtin_exp2f(st[mt][nt][1]);
        const float p2 = __builtin_exp2f(st[mt][nt][2]);
        const float p3 = __builtin_exp2f(st[mt][nt][3]);
        lac[nt][0] += p0 + p1;
        lac[nt][1] += p2 + p3;
        const auto plo = __builtin_amdgcn_cvt_pkrtz(p0, p1);
        const auto phi = __builtin_amdgcn_cvt_pkrtz(p2, p3);
        h4 pk = {(_Float16)plo[0], (_Float16)plo[1],
                 (_Float16)phi[0], (_Float16)phi[1]};
        *(h4*)&Ps[q][mt * 16 + quad * 4] = pk;  // wave-private rows
      }
    }

    // ---- O^T += V^T * P^T ----
#pragma unroll
    for (int ks = 0; ks < 2; ++ks) {
      h8 pf[2];
#pragma unroll
      for (int nt = 0; nt < 2; ++nt)
        pf[nt] = *(const h8*)&Ps[w * 32 + nt * 16 + l15][ks * 32 + quad * 8];
#pragma unroll
      for (int mt = 0; mt < 4; ++mt) {
        h8 vf = *(const h8*)&Vs[mt * 16 + l15][ks * 32 + quad * 8];
#pragma unroll
        for (int nt = 0; nt < 2; ++nt)
          oc[mt][nt] = __builtin_amdgcn_mfma_f32_16x16x32_f16(
              vf, pf[nt], oc[mt][nt], 0, 0, 0);
      }
    }
  }

  // ---- epilogue: reduce l across quads, write O/l (f16) + l (f32) ----
#pragma unroll
  for (int nt = 0; nt < 2; ++nt) {
    float l = lac[nt][0] + lac[nt][1];
    l += __shfl_xor(l, 16);
    l += __shfl_xor(l, 32);
    const float inv = 1.f / l;
    const int qi = n0 + w * 32 + nt * 16 + l15;
    _Float16* od = op + (size_t)kq * BB * NN * DD +
                   ((size_t)b * NN + qi) * DD + h * 64;
#pragma unroll
    for (int mt = 0; mt < 4; ++mt) {
      const int dh = mt * 16 + quad * 4;
      h4 o = {(_Float16)(oc[mt][nt][0] * inv), (_Float16)(oc[mt][nt][1] * inv),
              (_Float16)(oc[mt][nt][2] * inv), (_Float16)(oc[mt][nt][3] * inv)};
      *(h4*)(od + dh) = o;
    }
    if (quad == 0)
      lp[(size_t)kq * BB * NH * NN + ((size_t)b * NH + h) * NN + qi] = l;
  }
}

// ---------------------------------------------------------------------------
// Kernel 2b: combine K-split halves: ho = (o0*l0 + o1*l1) / (l0+l1)
// ---------------------------------------------------------------------------
__global__ __launch_bounds__(256) void comb_k(
    const _Float16* __restrict__ op, const float* __restrict__ lp,
    _Float16* __restrict__ ho)
{
  const int idx = blockIdx.x * 256 + threadIdx.x;  // B*NN*64
  const int d8 = idx & 63;
  const int bn = idx >> 6;
  const int n = bn % NN, b = bn / NN;
  const int h = d8 >> 3;
  const size_t SL = (size_t)BB * NH * NN;
  const size_t SO = (size_t)BB * NN * DD;
  const size_t li = ((size_t)b * NH + h) * NN + n;
  const float l0 = lp[li];
  const float l1 = lp[SL + li];
  const float inv = 1.f / (l0 + l1);
  const float w0 = l0 * inv, w1 = l1 * inv;
  h8 o0 = *(const h8*)(op + (size_t)bn * DD + d8 * 8);
  h8 o1 = *(const h8*)(op + SO + (size_t)bn * DD + d8 * 8);
  h8 r;
#pragma unroll
  for (int i = 0; i < 8; ++i)
    r[i] = (_Float16)((float)o0[i] * w0 + (float)o1[i] * w1);
  *(h8*)(ho + (size_t)bn * DD + d8 * 8) = r;
}

// ---------------------------------------------------------------------------
// Kernel 3: out MFMA GEMM, 64(token) x 64(o) tiles, grid 576, BK=64 via two
// 32-wide slabs per barrier pair (8 phases x 16 MFMA, was 16 x 8).
// ---------------------------------------------------------------------------
__global__ __launch_bounds__(256) void out_gemm_k(
    const _Float16* __restrict__ ho, const _Float16* __restrict__ woh,
    const float* __restrict__ bias, float* __restrict__ out)
{
  __shared__ _Float16 Hs[2][64][32];
  __shared__ _Float16 Ws2[2][64][32];
  const int t = threadIdx.x;
  const int lane = t & 63, w = t >> 6;
  const int l15 = lane & 15, quad = lane >> 4;
  const int th = w & 1;    // token half (32)
  const int oh = w >> 1;   // o half (32)
  const int n0 = blockIdx.x * 64;
  const int o0 = blockIdx.y * 64;
  const int b  = blockIdx.z;
  const int srow = lane >> 2, scol = (lane & 3) * 8;

  f4 acc[2][2];  // [mt: token][nt: o]
#pragma unroll
  for (int mt = 0; mt < 2; ++mt)
#pragma unroll
    for (int nt = 0; nt < 2; ++nt) acc[mt][nt] = (f4)(0.f);

  for (int c0 = 0; c0 < DD; c0 += 64) {
#pragma unroll
    for (int s = 0; s < 2; ++s) {
      gload16(ho + ((size_t)b * NN + n0 + w * 16 + srow) * DD + c0 + s * 32 + scol,
              &Hs[s][0][0] + w * 512);
      gload16(woh + (size_t)(o0 + w * 16 + srow) * DD + c0 + s * 32 + scol,
              &Ws2[s][0][0] + w * 512);
    }
    __syncthreads();
    h8 hf[2][2], wf[2][2];
#pragma unroll
    for (int s = 0; s < 2; ++s) {
#pragma unroll
      for (int mt = 0; mt < 2; ++mt)
        hf[mt][s] = *(const h8*)&Hs[s][th * 32 + mt * 16 + l15][quad * 8];
#pragma unroll
      for (int nt = 0; nt < 2; ++nt)
        wf[nt][s] = *(const h8*)&Ws2[s][oh * 32 + nt * 16 + l15][quad * 8];
    }
#pragma unroll
    for (int s = 0; s < 2; ++s)
#pragma unroll
      for (int mt = 0; mt < 2; ++mt)
#pragma unroll
        for (int nt = 0; nt < 2; ++nt)
          acc[mt][nt] = __builtin_amdgcn_mfma_f32_16x16x32_f16(
              hf[mt][s], wf[nt][s], acc[mt][nt], 0, 0, 0);
    __syncthreads();
  }

#pragma unroll
  for (int nt = 0; nt < 2; ++nt) {
    const int o = o0 + oh * 32 + nt * 16 + l15;
    const float bv = bias[o];
#pragma unroll
    for (int mt = 0; mt < 2; ++mt) {
      const int token = n0 + th * 32 + mt * 16 + quad * 4;
      float4 v = {acc[mt][nt][0] + bv, acc[mt][nt][1] + bv,
                  acc[mt][nt][2] + bv, acc[mt][nt][3] + bv};
      *(float4*)(out + ((size_t)b * DD + o) * NN + token) = v;
    }
  }
}

extern "C" void kernel_launch(void* const* d_in, const int* in_sizes, int n_in,
                              void* d_out, int out_size, void* d_ws, size_t ws_size,
                              hipStream_t stream)
{
  (void)in_sizes; (void)n_in; (void)out_size; (void)ws_size;
  const float* x     = (const float*)d_in[0];
  const float* w_qkv = (const float*)d_in[1];
  const float* w_out = (const float*)d_in[2];
  const float* b_out = (const float*)d_in[3];
  const float* wav   = (const float*)d_in[4];
  float* out = (float*)d_out;

  const size_t SZ  = (size_t)BB * NH * NN * 64;   // 2,359,296 halves
  const size_t BTF = (size_t)NTBL * 128 * 32;     // 872,448 halves (dedup'd)

  _Float16* qb  = (_Float16*)d_ws;
  _Float16* kb  = qb + SZ;
  _Float16* vb  = kb + SZ;
  _Float16* btf = vb + SZ;                         // f16 bias table, 1.7 MB
  _Float16* op  = btf + BTF;                       // 2*SZ partial O (f16, normalized)
  float*    lpf = (float*)(op + 2 * SZ);           // 2*B*NH*NN f32
  _Float16* woh = (_Float16*)(lpf + 2 * (size_t)BB * NH * NN);
  // aliases (lifetime-disjoint):
  _Float16* ho  = qb;        // combine output (qb dead after attn)
  _Float16* xt  = op;        // x^T f16 (dead after qkv_gemm; op written by attn)
  _Float16* wqh = op + SZ;   // w_qkv f16 (dead after qkv_gemm)
  // total ws: ~14.2 + 1.7 + 9.4 + 0.3 + 0.5 = ~26 MB

  prep_k    <<<dim3(2304 + 1024 + 107), 256, 0, stream>>>(x, w_qkv, w_out, wav,
                                                          xt, wqh, woh, btf);
  qkv_gemm_k<<<dim3(NN / 128, D3 / 64, BB), 256, 0, stream>>>(xt, wqh, qb, kb, vb);
  attn_k    <<<dim3((NN / 128) * KSPLIT, NH, BB), 256, 0, stream>>>(qb, kb, vb, btf, op, lpf);
  comb_k    <<<dim3((BB * NN * 64) / 256), 256, 0, stream>>>(op, lpf, ho);
  out_gemm_k<<<dim3(NN / 64, DD / 64, BB), 256, 0, stream>>>(ho, woh, b_out, out);
}

// Round 11
// 158.055 us; speedup vs baseline: 1.0159x; 1.0159x over previous
//
#include <hip/hip_runtime.h>
#include <math.h>

#define BB 2
#define CC 512
#define NN 2304
#define NH 8
#define DD 512
#define D3 1536
#define WIDTH 48
#define C1 0.18033688f  // 0.125 * log2(e)

#define KSPLIT 2
#define KTILES 18        // 36 / KSPLIT
#define NTBL 213         // 71 deltas * 3 (qt mod 3)

typedef _Float16 h8 __attribute__((ext_vector_type(8)));
typedef _Float16 h4 __attribute__((ext_vector_type(4)));
typedef _Float16 h2 __attribute__((ext_vector_type(2)));
typedef float f4 __attribute__((ext_vector_type(4)));

__device__ __forceinline__ void gload16(const void* g, void* s) {
  __builtin_amdgcn_global_load_lds(
      (const __attribute__((address_space(1))) unsigned int*)g,
      (__attribute__((address_space(3))) unsigned int*)s, 16, 0, 0);
}

// ---------------------------------------------------------------------------
// Kernel 0 (merged prep): x transpose->f16, weight converts, Fresnel bias
// table (f16, dedup'd: entry depends only on (qt-kt, qt mod 3) since
// (qt,kt)->(qt+3,kt+3) shifts both tokens by 192 = 4 full rows).
// Table tbl = (qt-kt+35)*3 + qt%3, layout per tbl: [tid 128][j 32] in MFMA
// C-fragment order, pre-scaled by 0.1*log2e.
// ---------------------------------------------------------------------------
__global__ __launch_bounds__(256) void prep_k(
    const float* __restrict__ x, const float* __restrict__ wq,
    const float* __restrict__ wo, const float* __restrict__ wavp,
    _Float16* __restrict__ xt, _Float16* __restrict__ wqh,
    _Float16* __restrict__ woh, _Float16* __restrict__ btf)
{
  __shared__ float Ls[32][33];
  const int t = threadIdx.x;
  const int e = blockIdx.x;

  if (e < 2304) {
    // ---- transpose-convert x[b][c][n] fp32 -> xt[b][n][c] f16 ----
    const int n0 = (e % 72) * 32;
    const int c0 = ((e / 72) % 16) * 32;
    const int b  = e / 1152;
#pragma unroll
    for (int p = 0; p < 4; ++p) {
      const int cl = (t >> 5) + p * 8, nl = t & 31;
      Ls[cl][nl] = x[((size_t)b * CC + c0 + cl) * NN + n0 + nl];
    }
    __syncthreads();
#pragma unroll
    for (int p = 0; p < 2; ++p) {
      const int nl = (t >> 4) + p * 16, cl = (t & 15) * 2;
      h2 v = {(_Float16)Ls[cl][nl], (_Float16)Ls[cl + 1][nl]};
      *(h2*)(xt + ((size_t)b * NN + n0 + nl) * CC + c0 + cl) = v;
    }
  } else if (e < 3328) {
    // ---- convert w_qkv and w_out fp32 -> f16 ----
    const int idx = (e - 2304) * 256 + t;
    const int NQ = (D3 * CC) / 4;
    if (idx < NQ) {
      float4 v = *(const float4*)(wq + (size_t)idx * 4);
      h4 o = {(_Float16)v.x, (_Float16)v.y, (_Float16)v.z, (_Float16)v.w};
      *(h4*)(wqh + (size_t)idx * 4) = o;
    } else {
      const int j = idx - NQ;
      float4 v = *(const float4*)(wo + (size_t)j * 4);
      h4 o = {(_Float16)v.x, (_Float16)v.y, (_Float16)v.z, (_Float16)v.w};
      *(h4*)(woh + (size_t)j * 4) = o;
    }
  } else {
    // ---- Fresnel bias tables f16 (2 tables per 256-thread block) ----
    const int tbl = (e - 3328) * 2 + (t >> 7);
    if (tbl < NTBL) {
      const int tid = t & 127;
      const int dD = tbl / 3, qm = tbl % 3;
      const int qt0 = qm + 36;          // representative qtile, == qm (mod 3)
      const int kt0 = qt0 - (dD - 35);  // >= 1, keeps token indices positive
      const int w = tid >> 6, quad = (tid >> 4) & 3, l15 = tid & 15;
      const float pc = 6.283185307179586f / (fabsf(wavp[0]) * (float)WIDTH + 1e-6f);
      _Float16* o = btf + ((size_t)tbl * 128 + tid) * 32;
#pragma unroll
      for (int g = 0; g < 4; ++g) {
        h8 v;
#pragma unroll
        for (int el = 0; el < 8; ++el) {
          const int j = g * 8 + el;
          const int nt = j >> 4, mt = (j >> 2) & 3, r = j & 3;
          const int q = qt0 * 64 + w * 32 + nt * 16 + l15;
          const int k = kt0 * 64 + mt * 16 + quad * 4 + r;
          const float dy = (float)(q / WIDTH) - (float)(k / WIDTH);
          const float dx = (float)(q % WIDTH) - (float)(k % WIDTH);
          const float dist = sqrtf(dy * dy + dx * dx + 1e-8f);
          v[el] = (_Float16)(0.1f * __cosf(dist * pc) * 1.44269504f);
        }
        *(h8*)(o + g * 8) = v;
      }
    }
  }
}

// ---------------------------------------------------------------------------
// Kernel 1: qkv MFMA GEMM, 128(n) x 64(d) tiles (R9 body, byte-identical
// inner loop). XCD-L2-aware decode: 864 blocks = 8 XCDs x 108; each XCD owns
// a contiguous id range ordered n-major, so its xt working set (~3 n-panels
// x 2 b = ~1 MB) + wqh (1.5 MB) fit its private 4 MB L2 -> xt panel fetched
// once and reused 24x from L2 instead of re-fetched from L3/HBM.
// ---------------------------------------------------------------------------
__global__ __launch_bounds__(256) void qkv_gemm_k(
    const _Float16* __restrict__ xt, const _Float16* __restrict__ wqh,
    _Float16* __restrict__ qb, _Float16* __restrict__ kb,
    _Float16* __restrict__ vb)
{
  __shared__ _Float16 Xs[128][32];
  __shared__ _Float16 Ws[64][32];
  const int t = threadIdx.x;
  const int lane = t & 63, w = t >> 6;
  const int l15 = lane & 15, quad = lane >> 4;
  const int wm = w & 1;    // d half (32 wide)
  const int wn = w >> 1;   // n half (64 wide)

  // bijective XCD swizzle (864 = 8 * 108), n-major within each XCD range
  const int lin = blockIdx.x;
  const int id  = (lin & 7) * 108 + (lin >> 3);
  const int nt_ = id / 48;           // 0..17
  const int rem = id % 48;
  const int d_t = rem % 24;          // 0..23
  const int b   = rem / 24;          // 0..1
  const int n0 = nt_ * 128;
  const int d0 = d_t * 64;
  const bool isv = (d0 >= 2 * DD);
  const _Float16* xb = xt + (size_t)b * NN * CC;

  const int srow = lane >> 2, scol = (lane & 3) * 8;

  f4 acc[2][4];  // [mt: d][nt: n]
#pragma unroll
  for (int mt = 0; mt < 2; ++mt)
#pragma unroll
    for (int nt = 0; nt < 4; ++nt) acc[mt][nt] = (f4)(0.f);

  for (int c0 = 0; c0 < CC; c0 += 32) {
#pragma unroll
    for (int r = 0; r < 2; ++r) {
      const int ci = w + r * 4;
      gload16(xb + (size_t)(n0 + ci * 16 + srow) * CC + c0 + scol,
              &Xs[0][0] + ci * 512);
    }
    gload16(wqh + (size_t)(d0 + w * 16 + srow) * CC + c0 + scol,
            &Ws[0][0] + w * 512);
    __syncthreads();

    h8 wfr[2], xfr[4];
#pragma unroll
    for (int mt = 0; mt < 2; ++mt)
      wfr[mt] = *(const h8*)&Ws[wm * 32 + mt * 16 + l15][quad * 8];
#pragma unroll
    for (int nt = 0; nt < 4; ++nt)
      xfr[nt] = *(const h8*)&Xs[wn * 64 + nt * 16 + l15][quad * 8];

    if (!isv) {
#pragma unroll
      for (int mt = 0; mt < 2; ++mt)
#pragma unroll
        for (int nt = 0; nt < 4; ++nt)
          acc[mt][nt] = __builtin_amdgcn_mfma_f32_16x16x32_f16(
              wfr[mt], xfr[nt], acc[mt][nt], 0, 0, 0);
    } else {
#pragma unroll
      for (int mt = 0; mt < 2; ++mt)
#pragma unroll
        for (int nt = 0; nt < 4; ++nt)
          acc[mt][nt] = __builtin_amdgcn_mfma_f32_16x16x32_f16(
              xfr[nt], wfr[mt], acc[mt][nt], 0, 0, 0);
    }
    __syncthreads();
  }

  if (!isv) {
    const int which = d0 >> 9;
    _Float16* buf = which == 0 ? qb : kb;
    const float qs = (which == 0) ? C1 : 1.0f;  // fold softmax scale into Q
    const int h = (d0 & 511) >> 6;
#pragma unroll
    for (int mt = 0; mt < 2; ++mt) {
      const int dh = wm * 32 + mt * 16 + quad * 4;
#pragma unroll
      for (int nt = 0; nt < 4; ++nt) {
        const int token = n0 + wn * 64 + nt * 16 + l15;
        h4 o = {(_Float16)(acc[mt][nt][0] * qs), (_Float16)(acc[mt][nt][1] * qs),
                (_Float16)(acc[mt][nt][2] * qs), (_Float16)(acc[mt][nt][3] * qs)};
        *(h4*)(buf + (((size_t)b * NH + h) * NN + token) * 64 + dh) = o;
      }
    }
  } else {
    const int h = (d0 - 2 * DD) >> 6;
#pragma unroll
    for (int mt = 0; mt < 2; ++mt) {
      const int dh = wm * 32 + mt * 16 + l15;
#pragma unroll
      for (int nt = 0; nt < 4; ++nt) {
        const int token = n0 + wn * 64 + nt * 16 + quad * 4;
        h4 o = {(_Float16)acc[mt][nt][0], (_Float16)acc[mt][nt][1],
                (_Float16)acc[mt][nt][2], (_Float16)acc[mt][nt][3]};
        *(h4*)(vb + (((size_t)b * NH + h) * 64 + dh) * NN + token) = o;
      }
    }
  }
}

// ---------------------------------------------------------------------------
// Kernel 2: MFMA flash attention — R4/R9 champion body, byte-identical inner
// loop. XCD-L2-aware decode: 576 blocks = 8 XCDs x 72; each XCD owns exactly
// 2 (b,h) pairs -> K/V working set 1.18 MB fits its 4 MB L2 (R6 measured
// this swizzle cutting FETCH 27.6 -> 13.6 MB).
// ---------------------------------------------------------------------------
__global__ __launch_bounds__(256, 4) void attn_k(
    const _Float16* __restrict__ qb, const _Float16* __restrict__ kb,
    const _Float16* __restrict__ vb, const _Float16* __restrict__ btf,
    _Float16* __restrict__ op, float* __restrict__ lp)
{
  __shared__ _Float16 Ks[64][72];
  __shared__ _Float16 Vs[64][72];
  __shared__ _Float16 Ps[128][72];

  const int t    = threadIdx.x;
  const int lane = t & 63;
  const int w    = t >> 6;          // wave 0..3 -> local q rows w*32..w*32+31
  const int l15  = lane & 15;
  const int quad = lane >> 4;

  // bijective XCD swizzle (576 = 8 * 72), (b,h)-major within each XCD range
  const int lin = blockIdx.x;
  const int id  = (lin & 7) * 72 + (lin >> 3);
  const int bh  = id / 36;             // 0..15 -> exactly 2 per XCD
  const int rm  = id % 36;
  const int qpair = rm >> 1;           // 128-row Q block index (0..17)
  const int kq    = rm & 1;            // K-split half
  const int b = bh >> 3, h = bh & 7;

  const int n0 = qpair * 128;
  const int qtile = qpair * 2 + (w >> 1);  // 64-row tile this wave sits in
  const size_t base = ((size_t)b * NH + h) * NN * 64;
  const _Float16* qp = qb + base;
  const _Float16* kp = kb + base;
  const _Float16* vp = vb + base;  // [dh][n]

  h8 qf[2][2];
#pragma unroll
  for (int nt = 0; nt < 2; ++nt)
#pragma unroll
    for (int ks = 0; ks < 2; ++ks)
      qf[nt][ks] = *(const h8*)(qp + (size_t)(n0 + w * 32 + nt * 16 + l15) * 64 +
                                ks * 32 + quad * 8);

  f4 oc[4][2];
#pragma unroll
  for (int mt = 0; mt < 4; ++mt)
#pragma unroll
    for (int nt = 0; nt < 2; ++nt) oc[mt][nt] = (f4)(0.f);
  float lac[2][2] = {};

  // bias table ptr: tbl = (qtile - ktile + 35)*3 + qtile%3; within-table tid
  // = (w&1)*64 + lane (the 128-tid layout's q-half select is our w&1).
  const _Float16* bp =
      btf + ((size_t)((qtile - kq * KTILES + 35) * 3 + qtile % 3) * 128 +
             (w & 1) * 64 + lane) * 32;

  for (int kt = 0; kt < KTILES; ++kt) {
    const int k0 = (kq * KTILES + kt) * 64;
    h8 kr[2], vr[2], bfr[4];
#pragma unroll
    for (int r = 0; r < 2; ++r) {
      const int c = t + r * 256;
      const int row = c >> 3, off = (c & 7) * 8;
      kr[r] = *(const h8*)(kp + (size_t)(k0 + row) * 64 + off);
      vr[r] = *(const h8*)(vp + (size_t)row * NN + k0 + off);
    }
#pragma unroll
    for (int r = 0; r < 4; ++r) bfr[r] = *(const h8*)(bp + r * 8);
    bp -= 3 * 128 * 32;  // next ktile: delta decreases by 1 -> tbl index -3
    __syncthreads();
#pragma unroll
    for (int r = 0; r < 2; ++r) {
      const int c = t + r * 256;
      const int row = c >> 3, off = (c & 7) * 8;
      *(h8*)&Ks[row][off] = kr[r];
      *(h8*)&Vs[row][off] = vr[r];
    }
    __syncthreads();

    // ---- S^T = K * Q'^T, accumulator seeded with bias fragment ----
    f4 st[4][2];
#pragma unroll
    for (int mt = 0; mt < 4; ++mt)
#pragma unroll
      for (int nt = 0; nt < 2; ++nt) {
        const int jb = nt * 16 + mt * 4;
        f4 s = {(float)bfr[jb >> 3][(jb & 7) + 0],
                (float)bfr[jb >> 3][(jb & 7) + 1],
                (float)bfr[jb >> 3][(jb & 7) + 2],
                (float)bfr[jb >> 3][(jb & 7) + 3]};
        st[mt][nt] = s;
      }
#pragma unroll
    for (int ks = 0; ks < 2; ++ks) {
#pragma unroll
      for (int mt = 0; mt < 4; ++mt) {
        h8 kf = *(const h8*)&Ks[mt * 16 + l15][ks * 32 + quad * 8];
#pragma unroll
        for (int nt = 0; nt < 2; ++nt)
          st[mt][nt] = __builtin_amdgcn_mfma_f32_16x16x32_f16(
              kf, qf[nt][ks], st[mt][nt], 0, 0, 0);
      }
    }

    // ---- p = exp2(s), no max tracking ----
#pragma unroll
    for (int nt = 0; nt < 2; ++nt) {
      const int q = w * 32 + nt * 16 + l15;
#pragma unroll
      for (int mt = 0; mt < 4; ++mt) {
        const float p0 = __builtin_exp2f(st[mt][nt][0]);
        const float p1 = __builtin_exp2f(st[mt][nt][1]);
        const float p2 = __builtin_exp2f(st[mt][nt][2]);
        const float p3 = __builtin_exp2f(st[mt][nt][3]);
        lac[nt][0] += p0 + p1;
        lac[nt][1] += p2 + p3;
        const auto plo = __builtin_amdgcn_cvt_pkrtz(p0, p1);
        const auto phi = __builtin_amdgcn_cvt_pkrtz(p2, p3);
        h4 pk = {(_Float16)plo[0], (_Float16)plo[1],
                 (_Float16)phi[0], (_Float16)phi[1]};
        *(h4*)&Ps[q][mt * 16 + quad * 4] = pk;  // wave-private rows
      }
    }

    // ---- O^T += V^T * P^T ----
#pragma unroll
    for (int ks = 0; ks < 2; ++ks) {
      h8 pf[2];
#pragma unroll
      for (int nt = 0; nt < 2; ++nt)
        pf[nt] = *(const h8*)&Ps[w * 32 + nt * 16 + l15][ks * 32 + quad * 8];
#pragma unroll
      for (int mt = 0; mt < 4; ++mt) {
        h8 vf = *(const h8*)&Vs[mt * 16 + l15][ks * 32 + quad * 8];
#pragma unroll
        for (int nt = 0; nt < 2; ++nt)
          oc[mt][nt] = __builtin_amdgcn_mfma_f32_16x16x32_f16(
              vf, pf[nt], oc[mt][nt], 0, 0, 0);
      }
    }
  }

  // ---- epilogue: reduce l across quads, write O/l (f16) + l (f32) ----
#pragma unroll
  for (int nt = 0; nt < 2; ++nt) {
    float l = lac[nt][0] + lac[nt][1];
    l += __shfl_xor(l, 16);
    l += __shfl_xor(l, 32);
    const float inv = 1.f / l;
    const int qi = n0 + w * 32 + nt * 16 + l15;
    _Float16* od = op + (size_t)kq * BB * NN * DD +
                   ((size_t)b * NN + qi) * DD + h * 64;
#pragma unroll
    for (int mt = 0; mt < 4; ++mt) {
      const int dh = mt * 16 + quad * 4;
      h4 o = {(_Float16)(oc[mt][nt][0] * inv), (_Float16)(oc[mt][nt][1] * inv),
              (_Float16)(oc[mt][nt][2] * inv), (_Float16)(oc[mt][nt][3] * inv)};
      *(h4*)(od + dh) = o;
    }
    if (quad == 0)
      lp[(size_t)kq * BB * NH * NN + ((size_t)b * NH + h) * NN + qi] = l;
  }
}

// ---------------------------------------------------------------------------
// Kernel 2b: combine K-split halves: ho = (o0*l0 + o1*l1) / (l0+l1)
// (pure streaming, no reuse -> no swizzle needed)
// ---------------------------------------------------------------------------
__global__ __launch_bounds__(256) void comb_k(
    const _Float16* __restrict__ op, const float* __restrict__ lp,
    _Float16* __restrict__ ho)
{
  const int idx = blockIdx.x * 256 + threadIdx.x;  // B*NN*64
  const int d8 = idx & 63;
  const int bn = idx >> 6;
  const int n = bn % NN, b = bn / NN;
  const int h = d8 >> 3;
  const size_t SL = (size_t)BB * NH * NN;
  const size_t SO = (size_t)BB * NN * DD;
  const size_t li = ((size_t)b * NH + h) * NN + n;
  const float l0 = lp[li];
  const float l1 = lp[SL + li];
  const float inv = 1.f / (l0 + l1);
  const float w0 = l0 * inv, w1 = l1 * inv;
  h8 o0 = *(const h8*)(op + (size_t)bn * DD + d8 * 8);
  h8 o1 = *(const h8*)(op + SO + (size_t)bn * DD + d8 * 8);
  h8 r;
#pragma unroll
  for (int i = 0; i < 8; ++i)
    r[i] = (_Float16)((float)o0[i] * w0 + (float)o1[i] * w1);
  *(h8*)(ho + (size_t)bn * DD + d8 * 8) = r;
}

// ---------------------------------------------------------------------------
// Kernel 3: out MFMA GEMM, 64x64 tiles (R9 body). XCD-L2-aware decode:
// 576 = 8 x 72, n-major per XCD -> ho slice (~0.7 MB) + woh (0.5 MB) fit L2,
// so each ho panel is fetched once and reused 8x (o-tiles) from L2.
// ---------------------------------------------------------------------------
__global__ __launch_bounds__(256) void out_gemm_k(
    const _Float16* __restrict__ ho, const _Float16* __restrict__ woh,
    const float* __restrict__ bias, float* __restrict__ out)
{
  __shared__ _Float16 Hs[64][32];
  __shared__ _Float16 Ws2[64][32];
  const int t = threadIdx.x;
  const int lane = t & 63, w = t >> 6;
  const int l15 = lane & 15, quad = lane >> 4;
  const int th = w & 1;    // token half (32)
  const int oh = w >> 1;   // o half (32)

  // bijective XCD swizzle (576 = 8 * 72), n-major within each XCD range
  const int lin = blockIdx.x;
  const int id  = (lin & 7) * 72 + (lin >> 3);
  const int nt_ = id / 16;            // 0..35
  const int rem = id % 16;
  const int o_t = rem % 8;            // 0..7
  const int b   = rem / 8;            // 0..1
  const int n0 = nt_ * 64;
  const int o0 = o_t * 64;

  const int srow = lane >> 2, scol = (lane & 3) * 8;

  f4 acc[2][2];  // [mt: token][nt: o]
#pragma unroll
  for (int mt = 0; mt < 2; ++mt)
#pragma unroll
    for (int nt = 0; nt < 2; ++nt) acc[mt][nt] = (f4)(0.f);

  for (int c0 = 0; c0 < DD; c0 += 32) {
    gload16(ho + ((size_t)b * NN + n0 + w * 16 + srow) * DD + c0 + scol,
            &Hs[0][0] + w * 512);
    gload16(woh + (size_t)(o0 + w * 16 + srow) * DD + c0 + scol,
            &Ws2[0][0] + w * 512);
    __syncthreads();
    h8 hf[2], wf[2];
#pragma unroll
    for (int mt = 0; mt < 2; ++mt)
      hf[mt] = *(const h8*)&Hs[th * 32 + mt * 16 + l15][quad * 8];
#pragma unroll
    for (int nt = 0; nt < 2; ++nt)
      wf[nt] = *(const h8*)&Ws2[oh * 32 + nt * 16 + l15][quad * 8];
#pragma unroll
    for (int mt = 0; mt < 2; ++mt)
#pragma unroll
      for (int nt = 0; nt < 2; ++nt)
        acc[mt][nt] = __builtin_amdgcn_mfma_f32_16x16x32_f16(
            hf[mt], wf[nt], acc[mt][nt], 0, 0, 0);
    __syncthreads();
  }

#pragma unroll
  for (int nt = 0; nt < 2; ++nt) {
    const int o = o0 + oh * 32 + nt * 16 + l15;
    const float bv = bias[o];
#pragma unroll
    for (int mt = 0; mt < 2; ++mt) {
      const int token = n0 + th * 32 + mt * 16 + quad * 4;
      float4 v = {acc[mt][nt][0] + bv, acc[mt][nt][1] + bv,
                  acc[mt][nt][2] + bv, acc[mt][nt][3] + bv};
      *(float4*)(out + ((size_t)b * DD + o) * NN + token) = v;
    }
  }
}

extern "C" void kernel_launch(void* const* d_in, const int* in_sizes, int n_in,
                              void* d_out, int out_size, void* d_ws, size_t ws_size,
                              hipStream_t stream)
{
  (void)in_sizes; (void)n_in; (void)out_size; (void)ws_size;
  const float* x     = (const float*)d_in[0];
  const float* w_qkv = (const float*)d_in[1];
  const float* w_out = (const float*)d_in[2];
  const float* b_out = (const float*)d_in[3];
  const float* wav   = (const float*)d_in[4];
  float* out = (float*)d_out;

  const size_t SZ  = (size_t)BB * NH * NN * 64;   // 2,359,296 halves
  const size_t BTF = (size_t)NTBL * 128 * 32;     // 872,448 halves (dedup'd)

  _Float16* qb  = (_Float16*)d_ws;
  _Float16* kb  = qb + SZ;
  _Float16* vb  = kb + SZ;
  _Float16* btf = vb + SZ;                         // f16 bias table, 1.7 MB
  _Float16* op  = btf + BTF;                       // 2*SZ partial O (f16, normalized)
  float*    lpf = (float*)(op + 2 * SZ);           // 2*B*NH*NN f32
  _Float16* woh = (_Float16*)(lpf + 2 * (size_t)BB * NH * NN);
  // aliases (lifetime-disjoint):
  _Float16* ho  = qb;        // combine output (qb dead after attn)
  _Float16* xt  = op;        // x^T f16 (dead after qkv_gemm; op written by attn)
  _Float16* wqh = op + SZ;   // w_qkv f16 (dead after qkv_gemm)
  // total ws: ~14.2 + 1.7 + 9.4 + 0.3 + 0.5 = ~26 MB

  prep_k    <<<dim3(2304 + 1024 + 107), 256, 0, stream>>>(x, w_qkv, w_out, wav,
                                                          xt, wqh, woh, btf);
  qkv_gemm_k<<<dim3(864), 256, 0, stream>>>(xt, wqh, qb, kb, vb);
  attn_k    <<<dim3(576), 256, 0, stream>>>(qb, kb, vb, btf, op, lpf);
  comb_k    <<<dim3((BB * NN * 64) / 256), 256, 0, stream>>>(op, lpf, ho);
  out_gemm_k<<<dim3(576), 256, 0, stream>>>(ho, woh, b_out, out);
}

// Round 12
// 149.872 us; speedup vs baseline: 1.0713x; 1.0546x over previous
//
#include <hip/hip_runtime.h>
#include <math.h>

#define BB 2
#define CC 512
#define NN 2304
#define NH 8
#define DD 512
#define D3 1536
#define WIDTH 48
#define C1 0.18033688f  // 0.125 * log2(e)

#define KSPLIT 3
#define KTILES 12        // 36 / KSPLIT
#define NTBL 213         // 71 deltas * 3 (qt mod 3)

typedef _Float16 h8 __attribute__((ext_vector_type(8)));
typedef _Float16 h4 __attribute__((ext_vector_type(4)));
typedef _Float16 h2 __attribute__((ext_vector_type(2)));
typedef float f4 __attribute__((ext_vector_type(4)));

__device__ __forceinline__ void gload16(const void* g, void* s) {
  __builtin_amdgcn_global_load_lds(
      (const __attribute__((address_space(1))) unsigned int*)g,
      (__attribute__((address_space(3))) unsigned int*)s, 16, 0, 0);
}

// ---------------------------------------------------------------------------
// Kernel 0 (merged prep): x transpose->f16, weight converts, Fresnel bias
// table (f16, dedup'd: entry depends only on (qt-kt, qt mod 3) since
// (qt,kt)->(qt+3,kt+3) shifts both tokens by 192 = 4 full rows).
// Table tbl = (qt-kt+35)*3 + qt%3, layout per tbl: [tid 128][j 32] in MFMA
// C-fragment order, pre-scaled by 0.1*log2e.
// ---------------------------------------------------------------------------
__global__ __launch_bounds__(256) void prep_k(
    const float* __restrict__ x, const float* __restrict__ wq,
    const float* __restrict__ wo, const float* __restrict__ wavp,
    _Float16* __restrict__ xt, _Float16* __restrict__ wqh,
    _Float16* __restrict__ woh, _Float16* __restrict__ btf)
{
  __shared__ float Ls[32][33];
  const int t = threadIdx.x;
  const int e = blockIdx.x;

  if (e < 2304) {
    // ---- transpose-convert x[b][c][n] fp32 -> xt[b][n][c] f16 ----
    const int n0 = (e % 72) * 32;
    const int c0 = ((e / 72) % 16) * 32;
    const int b  = e / 1152;
#pragma unroll
    for (int p = 0; p < 4; ++p) {
      const int cl = (t >> 5) + p * 8, nl = t & 31;
      Ls[cl][nl] = x[((size_t)b * CC + c0 + cl) * NN + n0 + nl];
    }
    __syncthreads();
#pragma unroll
    for (int p = 0; p < 2; ++p) {
      const int nl = (t >> 4) + p * 16, cl = (t & 15) * 2;
      h2 v = {(_Float16)Ls[cl][nl], (_Float16)Ls[cl + 1][nl]};
      *(h2*)(xt + ((size_t)b * NN + n0 + nl) * CC + c0 + cl) = v;
    }
  } else if (e < 3328) {
    // ---- convert w_qkv and w_out fp32 -> f16 ----
    const int idx = (e - 2304) * 256 + t;
    const int NQ = (D3 * CC) / 4;
    if (idx < NQ) {
      float4 v = *(const float4*)(wq + (size_t)idx * 4);
      h4 o = {(_Float16)v.x, (_Float16)v.y, (_Float16)v.z, (_Float16)v.w};
      *(h4*)(wqh + (size_t)idx * 4) = o;
    } else {
      const int j = idx - NQ;
      float4 v = *(const float4*)(wo + (size_t)j * 4);
      h4 o = {(_Float16)v.x, (_Float16)v.y, (_Float16)v.z, (_Float16)v.w};
      *(h4*)(woh + (size_t)j * 4) = o;
    }
  } else {
    // ---- Fresnel bias tables f16 (2 tables per 256-thread block) ----
    const int tbl = (e - 3328) * 2 + (t >> 7);
    if (tbl < NTBL) {
      const int tid = t & 127;
      const int dD = tbl / 3, qm = tbl % 3;
      const int qt0 = qm + 36;          // representative qtile, == qm (mod 3)
      const int kt0 = qt0 - (dD - 35);  // >= 1, keeps token indices positive
      const int w = tid >> 6, quad = (tid >> 4) & 3, l15 = tid & 15;
      const float pc = 6.283185307179586f / (fabsf(wavp[0]) * (float)WIDTH + 1e-6f);
      _Float16* o = btf + ((size_t)tbl * 128 + tid) * 32;
#pragma unroll
      for (int g = 0; g < 4; ++g) {
        h8 v;
#pragma unroll
        for (int el = 0; el < 8; ++el) {
          const int j = g * 8 + el;
          const int nt = j >> 4, mt = (j >> 2) & 3, r = j & 3;
          const int q = qt0 * 64 + w * 32 + nt * 16 + l15;
          const int k = kt0 * 64 + mt * 16 + quad * 4 + r;
          const float dy = (float)(q / WIDTH) - (float)(k / WIDTH);
          const float dx = (float)(q % WIDTH) - (float)(k % WIDTH);
          const float dist = sqrtf(dy * dy + dx * dx + 1e-8f);
          v[el] = (_Float16)(0.1f * __cosf(dist * pc) * 1.44269504f);
        }
        *(h8*)(o + g * 8) = v;
      }
    }
  }
}

// ---------------------------------------------------------------------------
// Kernel 1: qkv MFMA GEMM, 128(n) x 64(d) tiles (R9 body). XCD-L2-aware
// decode: 864 = 8 x 108, n-major per XCD (R11, kept).
// ---------------------------------------------------------------------------
__global__ __launch_bounds__(256) void qkv_gemm_k(
    const _Float16* __restrict__ xt, const _Float16* __restrict__ wqh,
    _Float16* __restrict__ qb, _Float16* __restrict__ kb,
    _Float16* __restrict__ vb)
{
  __shared__ _Float16 Xs[128][32];
  __shared__ _Float16 Ws[64][32];
  const int t = threadIdx.x;
  const int lane = t & 63, w = t >> 6;
  const int l15 = lane & 15, quad = lane >> 4;
  const int wm = w & 1;    // d half (32 wide)
  const int wn = w >> 1;   // n half (64 wide)

  // bijective XCD swizzle (864 = 8 * 108), n-major within each XCD range
  const int lin = blockIdx.x;
  const int id  = (lin & 7) * 108 + (lin >> 3);
  const int nt_ = id / 48;           // 0..17
  const int rem = id % 48;
  const int d_t = rem % 24;          // 0..23
  const int b   = rem / 24;          // 0..1
  const int n0 = nt_ * 128;
  const int d0 = d_t * 64;
  const bool isv = (d0 >= 2 * DD);
  const _Float16* xb = xt + (size_t)b * NN * CC;

  const int srow = lane >> 2, scol = (lane & 3) * 8;

  f4 acc[2][4];  // [mt: d][nt: n]
#pragma unroll
  for (int mt = 0; mt < 2; ++mt)
#pragma unroll
    for (int nt = 0; nt < 4; ++nt) acc[mt][nt] = (f4)(0.f);

  for (int c0 = 0; c0 < CC; c0 += 32) {
#pragma unroll
    for (int r = 0; r < 2; ++r) {
      const int ci = w + r * 4;
      gload16(xb + (size_t)(n0 + ci * 16 + srow) * CC + c0 + scol,
              &Xs[0][0] + ci * 512);
    }
    gload16(wqh + (size_t)(d0 + w * 16 + srow) * CC + c0 + scol,
            &Ws[0][0] + w * 512);
    __syncthreads();

    h8 wfr[2], xfr[4];
#pragma unroll
    for (int mt = 0; mt < 2; ++mt)
      wfr[mt] = *(const h8*)&Ws[wm * 32 + mt * 16 + l15][quad * 8];
#pragma unroll
    for (int nt = 0; nt < 4; ++nt)
      xfr[nt] = *(const h8*)&Xs[wn * 64 + nt * 16 + l15][quad * 8];

    if (!isv) {
#pragma unroll
      for (int mt = 0; mt < 2; ++mt)
#pragma unroll
        for (int nt = 0; nt < 4; ++nt)
          acc[mt][nt] = __builtin_amdgcn_mfma_f32_16x16x32_f16(
              wfr[mt], xfr[nt], acc[mt][nt], 0, 0, 0);
    } else {
#pragma unroll
      for (int mt = 0; mt < 2; ++mt)
#pragma unroll
        for (int nt = 0; nt < 4; ++nt)
          acc[mt][nt] = __builtin_amdgcn_mfma_f32_16x16x32_f16(
              xfr[nt], wfr[mt], acc[mt][nt], 0, 0, 0);
    }
    __syncthreads();
  }

  if (!isv) {
    const int which = d0 >> 9;
    _Float16* buf = which == 0 ? qb : kb;
    const float qs = (which == 0) ? C1 : 1.0f;  // fold softmax scale into Q
    const int h = (d0 & 511) >> 6;
#pragma unroll
    for (int mt = 0; mt < 2; ++mt) {
      const int dh = wm * 32 + mt * 16 + quad * 4;
#pragma unroll
      for (int nt = 0; nt < 4; ++nt) {
        const int token = n0 + wn * 64 + nt * 16 + l15;
        h4 o = {(_Float16)(acc[mt][nt][0] * qs), (_Float16)(acc[mt][nt][1] * qs),
                (_Float16)(acc[mt][nt][2] * qs), (_Float16)(acc[mt][nt][3] * qs)};
        *(h4*)(buf + (((size_t)b * NH + h) * NN + token) * 64 + dh) = o;
      }
    }
  } else {
    const int h = (d0 - 2 * DD) >> 6;
#pragma unroll
    for (int mt = 0; mt < 2; ++mt) {
      const int dh = wm * 32 + mt * 16 + l15;
#pragma unroll
      for (int nt = 0; nt < 4; ++nt) {
        const int token = n0 + wn * 64 + nt * 16 + quad * 4;
        h4 o = {(_Float16)acc[mt][nt][0], (_Float16)acc[mt][nt][1],
                (_Float16)acc[mt][nt][2], (_Float16)acc[mt][nt][3]};
        *(h4*)(vb + (((size_t)b * NH + h) * 64 + dh) * NN + token) = o;
      }
    }
  }
}

// ---------------------------------------------------------------------------
// Kernel 2: MFMA flash attention — champion body, K-SPLIT x3 (KTILES=12).
// 864 blocks = 3.375 blocks/CU (was 2.25): +50% co-resident waves. R2's
// KSPLIT=3 regression was cross-XCD L2 thrash; the bijective swizzle keeps
// exactly 2 (b,h) pairs per XCD (864 = 8 x 108 = 8 x 2 pairs x 54), so K/V
// stay L2-resident (R11 measured FETCH 27.6 -> 13.6 MB with this swizzle).
// ---------------------------------------------------------------------------
__global__ __launch_bounds__(256, 4) void attn_k(
    const _Float16* __restrict__ qb, const _Float16* __restrict__ kb,
    const _Float16* __restrict__ vb, const _Float16* __restrict__ btf,
    _Float16* __restrict__ op, float* __restrict__ lp)
{
  __shared__ _Float16 Ks[64][72];
  __shared__ _Float16 Vs[64][72];
  __shared__ _Float16 Ps[128][72];

  const int t    = threadIdx.x;
  const int lane = t & 63;
  const int w    = t >> 6;          // wave 0..3 -> local q rows w*32..w*32+31
  const int l15  = lane & 15;
  const int quad = lane >> 4;

  // bijective XCD swizzle (864 = 8 * 108), (b,h)-major within each XCD range
  const int lin = blockIdx.x;
  const int id  = (lin & 7) * 108 + (lin >> 3);
  const int bh  = id / 54;             // 0..15 -> exactly 2 per XCD
  const int rm  = id % 54;
  const int qpair = rm / 3;            // 128-row Q block index (0..17)
  const int kq    = rm % 3;            // K-split third
  const int b = bh >> 3, h = bh & 7;

  const int n0 = qpair * 128;
  const int qtile = qpair * 2 + (w >> 1);  // 64-row tile this wave sits in
  const size_t base = ((size_t)b * NH + h) * NN * 64;
  const _Float16* qp = qb + base;
  const _Float16* kp = kb + base;
  const _Float16* vp = vb + base;  // [dh][n]

  h8 qf[2][2];
#pragma unroll
  for (int nt = 0; nt < 2; ++nt)
#pragma unroll
    for (int ks = 0; ks < 2; ++ks)
      qf[nt][ks] = *(const h8*)(qp + (size_t)(n0 + w * 32 + nt * 16 + l15) * 64 +
                                ks * 32 + quad * 8);

  f4 oc[4][2];
#pragma unroll
  for (int mt = 0; mt < 4; ++mt)
#pragma unroll
    for (int nt = 0; nt < 2; ++nt) oc[mt][nt] = (f4)(0.f);
  float lac[2][2] = {};

  // bias table ptr: tbl = (qtile - ktile + 35)*3 + qtile%3; within-table tid
  // = (w&1)*64 + lane (the 128-tid layout's q-half select is our w&1).
  const _Float16* bp =
      btf + ((size_t)((qtile - kq * KTILES + 35) * 3 + qtile % 3) * 128 +
             (w & 1) * 64 + lane) * 32;

  for (int kt = 0; kt < KTILES; ++kt) {
    const int k0 = (kq * KTILES + kt) * 64;
    h8 kr[2], vr[2], bfr[4];
#pragma unroll
    for (int r = 0; r < 2; ++r) {
      const int c = t + r * 256;
      const int row = c >> 3, off = (c & 7) * 8;
      kr[r] = *(const h8*)(kp + (size_t)(k0 + row) * 64 + off);
      vr[r] = *(const h8*)(vp + (size_t)row * NN + k0 + off);
    }
#pragma unroll
    for (int r = 0; r < 4; ++r) bfr[r] = *(const h8*)(bp + r * 8);
    bp -= 3 * 128 * 32;  // next ktile: delta decreases by 1 -> tbl index -3
    __syncthreads();
#pragma unroll
    for (int r = 0; r < 2; ++r) {
      const int c = t + r * 256;
      const int row = c >> 3, off = (c & 7) * 8;
      *(h8*)&Ks[row][off] = kr[r];
      *(h8*)&Vs[row][off] = vr[r];
    }
    __syncthreads();

    // ---- S^T = K * Q'^T, accumulator seeded with bias fragment ----
    f4 st[4][2];
#pragma unroll
    for (int mt = 0; mt < 4; ++mt)
#pragma unroll
      for (int nt = 0; nt < 2; ++nt) {
        const int jb = nt * 16 + mt * 4;
        f4 s = {(float)bfr[jb >> 3][(jb & 7) + 0],
                (float)bfr[jb >> 3][(jb & 7) + 1],
                (float)bfr[jb >> 3][(jb & 7) + 2],
                (float)bfr[jb >> 3][(jb & 7) + 3]};
        st[mt][nt] = s;
      }
#pragma unroll
    for (int ks = 0; ks < 2; ++ks) {
#pragma unroll
      for (int mt = 0; mt < 4; ++mt) {
        h8 kf = *(const h8*)&Ks[mt * 16 + l15][ks * 32 + quad * 8];
#pragma unroll
        for (int nt = 0; nt < 2; ++nt)
          st[mt][nt] = __builtin_amdgcn_mfma_f32_16x16x32_f16(
              kf, qf[nt][ks], st[mt][nt], 0, 0, 0);
      }
    }

    // ---- p = exp2(s), no max tracking ----
#pragma unroll
    for (int nt = 0; nt < 2; ++nt) {
      const int q = w * 32 + nt * 16 + l15;
#pragma unroll
      for (int mt = 0; mt < 4; ++mt) {
        const float p0 = __builtin_exp2f(st[mt][nt][0]);
        const float p1 = __builtin_exp2f(st[mt][nt][1]);
        const float p2 = __builtin_exp2f(st[mt][nt][2]);
        const float p3 = __builtin_exp2f(st[mt][nt][3]);
        lac[nt][0] += p0 + p1;
        lac[nt][1] += p2 + p3;
        const auto plo = __builtin_amdgcn_cvt_pkrtz(p0, p1);
        const auto phi = __builtin_amdgcn_cvt_pkrtz(p2, p3);
        h4 pk = {(_Float16)plo[0], (_Float16)plo[1],
                 (_Float16)phi[0], (_Float16)phi[1]};
        *(h4*)&Ps[q][mt * 16 + quad * 4] = pk;  // wave-private rows
      }
    }

    // ---- O^T += V^T * P^T ----
#pragma unroll
    for (int ks = 0; ks < 2; ++ks) {
      h8 pf[2];
#pragma unroll
      for (int nt = 0; nt < 2; ++nt)
        pf[nt] = *(const h8*)&Ps[w * 32 + nt * 16 + l15][ks * 32 + quad * 8];
#pragma unroll
      for (int mt = 0; mt < 4; ++mt) {
        h8 vf = *(const h8*)&Vs[mt * 16 + l15][ks * 32 + quad * 8];
#pragma unroll
        for (int nt = 0; nt < 2; ++nt)
          oc[mt][nt] = __builtin_amdgcn_mfma_f32_16x16x32_f16(
              vf, pf[nt], oc[mt][nt], 0, 0, 0);
      }
    }
  }

  // ---- epilogue: reduce l across quads, write O/l (f16) + l (f32) ----
#pragma unroll
  for (int nt = 0; nt < 2; ++nt) {
    float l = lac[nt][0] + lac[nt][1];
    l += __shfl_xor(l, 16);
    l += __shfl_xor(l, 32);
    const float inv = 1.f / l;
    const int qi = n0 + w * 32 + nt * 16 + l15;
    _Float16* od = op + (size_t)kq * BB * NN * DD +
                   ((size_t)b * NN + qi) * DD + h * 64;
#pragma unroll
    for (int mt = 0; mt < 4; ++mt) {
      const int dh = mt * 16 + quad * 4;
      h4 o = {(_Float16)(oc[mt][nt][0] * inv), (_Float16)(oc[mt][nt][1] * inv),
              (_Float16)(oc[mt][nt][2] * inv), (_Float16)(oc[mt][nt][3] * inv)};
      *(h4*)(od + dh) = o;
    }
    if (quad == 0)
      lp[(size_t)kq * BB * NH * NN + ((size_t)b * NH + h) * NN + qi] = l;
  }
}

// ---------------------------------------------------------------------------
// Kernel 2b: combine K-split thirds: ho = sum(o_i * l_i) / sum(l_i)
// ---------------------------------------------------------------------------
__global__ __launch_bounds__(256) void comb_k(
    const _Float16* __restrict__ op, const float* __restrict__ lp,
    _Float16* __restrict__ ho)
{
  const int idx = blockIdx.x * 256 + threadIdx.x;  // B*NN*64
  const int d8 = idx & 63;
  const int bn = idx >> 6;
  const int n = bn % NN, b = bn / NN;
  const int h = d8 >> 3;
  const size_t SL = (size_t)BB * NH * NN;
  const size_t SO = (size_t)BB * NN * DD;
  const size_t li = ((size_t)b * NH + h) * NN + n;
  const float l0 = lp[li];
  const float l1 = lp[SL + li];
  const float l2 = lp[2 * SL + li];
  const float inv = 1.f / (l0 + l1 + l2);
  const float w0 = l0 * inv, w1 = l1 * inv, w2 = l2 * inv;
  h8 o0 = *(const h8*)(op + (size_t)bn * DD + d8 * 8);
  h8 o1 = *(const h8*)(op + SO + (size_t)bn * DD + d8 * 8);
  h8 o2 = *(const h8*)(op + 2 * SO + (size_t)bn * DD + d8 * 8);
  h8 r;
#pragma unroll
  for (int i = 0; i < 8; ++i)
    r[i] = (_Float16)((float)o0[i] * w0 + (float)o1[i] * w1 + (float)o2[i] * w2);
  *(h8*)(ho + (size_t)bn * DD + d8 * 8) = r;
}

// ---------------------------------------------------------------------------
// Kernel 3: out MFMA GEMM, 64x64 tiles (R9 body). XCD-L2-aware decode:
// 576 = 8 x 72, n-major per XCD (R11, kept).
// ---------------------------------------------------------------------------
__global__ __launch_bounds__(256) void out_gemm_k(
    const _Float16* __restrict__ ho, const _Float16* __restrict__ woh,
    const float* __restrict__ bias, float* __restrict__ out)
{
  __shared__ _Float16 Hs[64][32];
  __shared__ _Float16 Ws2[64][32];
  const int t = threadIdx.x;
  const int lane = t & 63, w = t >> 6;
  const int l15 = lane & 15, quad = lane >> 4;
  const int th = w & 1;    // token half (32)
  const int oh = w >> 1;   // o half (32)

  // bijective XCD swizzle (576 = 8 * 72), n-major within each XCD range
  const int lin = blockIdx.x;
  const int id  = (lin & 7) * 72 + (lin >> 3);
  const int nt_ = id / 16;            // 0..35
  const int rem = id % 16;
  const int o_t = rem % 8;            // 0..7
  const int b   = rem / 8;            // 0..1
  const int n0 = nt_ * 64;
  const int o0 = o_t * 64;

  const int srow = lane >> 2, scol = (lane & 3) * 8;

  f4 acc[2][2];  // [mt: token][nt: o]
#pragma unroll
  for (int mt = 0; mt < 2; ++mt)
#pragma unroll
    for (int nt = 0; nt < 2; ++nt) acc[mt][nt] = (f4)(0.f);

  for (int c0 = 0; c0 < DD; c0 += 32) {
    gload16(ho + ((size_t)b * NN + n0 + w * 16 + srow) * DD + c0 + scol,
            &Hs[0][0] + w * 512);
    gload16(woh + (size_t)(o0 + w * 16 + srow) * DD + c0 + scol,
            &Ws2[0][0] + w * 512);
    __syncthreads();
    h8 hf[2], wf[2];
#pragma unroll
    for (int mt = 0; mt < 2; ++mt)
      hf[mt] = *(const h8*)&Hs[th * 32 + mt * 16 + l15][quad * 8];
#pragma unroll
    for (int nt = 0; nt < 2; ++nt)
      wf[nt] = *(const h8*)&Ws2[oh * 32 + nt * 16 + l15][quad * 8];
#pragma unroll
    for (int mt = 0; mt < 2; ++mt)
#pragma unroll
      for (int nt = 0; nt < 2; ++nt)
        acc[mt][nt] = __builtin_amdgcn_mfma_f32_16x16x32_f16(
            hf[mt], wf[nt], acc[mt][nt], 0, 0, 0);
    __syncthreads();
  }

#pragma unroll
  for (int nt = 0; nt < 2; ++nt) {
    const int o = o0 + oh * 32 + nt * 16 + l15;
    const float bv = bias[o];
#pragma unroll
    for (int mt = 0; mt < 2; ++mt) {
      const int token = n0 + th * 32 + mt * 16 + quad * 4;
      float4 v = {acc[mt][nt][0] + bv, acc[mt][nt][1] + bv,
                  acc[mt][nt][2] + bv, acc[mt][nt][3] + bv};
      *(float4*)(out + ((size_t)b * DD + o) * NN + token) = v;
    }
  }
}

extern "C" void kernel_launch(void* const* d_in, const int* in_sizes, int n_in,
                              void* d_out, int out_size, void* d_ws, size_t ws_size,
                              hipStream_t stream)
{
  (void)in_sizes; (void)n_in; (void)out_size; (void)ws_size;
  const float* x     = (const float*)d_in[0];
  const float* w_qkv = (const float*)d_in[1];
  const float* w_out = (const float*)d_in[2];
  const float* b_out = (const float*)d_in[3];
  const float* wav   = (const float*)d_in[4];
  float* out = (float*)d_out;

  const size_t SZ  = (size_t)BB * NH * NN * 64;   // 2,359,296 halves
  const size_t BTF = (size_t)NTBL * 128 * 32;     // 872,448 halves (dedup'd)

  _Float16* qb  = (_Float16*)d_ws;
  _Float16* kb  = qb + SZ;
  _Float16* vb  = kb + SZ;
  _Float16* btf = vb + SZ;                         // f16 bias table, 1.7 MB
  _Float16* op  = btf + BTF;                       // 3*SZ partial O (f16, normalized)
  float*    lpf = (float*)(op + 3 * SZ);           // 3*B*NH*NN f32
  _Float16* woh = (_Float16*)(lpf + 3 * (size_t)BB * NH * NN);
  // aliases (lifetime-disjoint):
  _Float16* ho  = qb;        // combine output (qb dead after attn)
  _Float16* xt  = op;        // x^T f16 (dead after qkv_gemm; op written by attn)
  _Float16* wqh = op + SZ;   // w_qkv f16 (dead after qkv_gemm)
  // total ws: ~14.2 + 1.7 + 14.2 + 0.45 + 0.5 = ~31 MB (R2-proven budget)

  prep_k    <<<dim3(2304 + 1024 + 107), 256, 0, stream>>>(x, w_qkv, w_out, wav,
                                                          xt, wqh, woh, btf);
  qkv_gemm_k<<<dim3(864), 256, 0, stream>>>(xt, wqh, qb, kb, vb);
  attn_k    <<<dim3(864), 256, 0, stream>>>(qb, kb, vb, btf, op, lpf);
  comb_k    <<<dim3((BB * NN * 64) / 256), 256, 0, stream>>>(op, lpf, ho);
  out_gemm_k<<<dim3(576), 256, 0, stream>>>(ho, woh, b_out, out);
}